// Round 1
// baseline (1829.294 us; speedup 1.0000x reference)
//
#include <hip/hip_runtime.h>

#define NTHREADS 512

typedef __attribute__((ext_vector_type(8))) short s16x8;
typedef __attribute__((ext_vector_type(4))) float f32x4;
typedef __attribute__((ext_vector_type(4))) unsigned int u32x4;

__device__ __forceinline__ unsigned short f2bf(float f) {
  unsigned u = __float_as_uint(f);
  u += 0x7fffu + ((u >> 16) & 1u);
  return (unsigned short)(u >> 16);
}
__device__ __forceinline__ float bf2f(unsigned short s) {
  return __uint_as_float(((unsigned)s) << 16);
}
__device__ __forceinline__ float sigm(float x) {
  return __builtin_amdgcn_rcpf(1.0f + __expf(-x));
}
__device__ __forceinline__ float tanh_fast(float x) {
  return 1.0f - 2.0f * __builtin_amdgcn_rcpf(1.0f + __expf(2.0f * x));
}
__device__ __forceinline__ f32x4 mfma_bf16(u32x4 a, u32x4 b, f32x4 c) {
  union { u32x4 u; s16x8 s; } ua, ub;
  ua.u = a; ub.u = b;
  return __builtin_amdgcn_mfma_f32_16x16x32_bf16(ua.s, ub.s, c, 0, 0, 0);
}

// ---------------- weight pre-pack ----------------
// W0p: layer0 combined [n=4H][K=416] (k<160: W_ih0, else W_hh0), bf16,
//      layout [nblk][kblk][16 n][8 k]  (B-fragment friendly: wave reads 1KB contiguous)
// W1p: layer1 combined K=512 (k<256: W_ih1, else W_hh1), same layout, KB=64
// b0/b1: b_ih + b_hh pre-summed, f32
__global__ void pack_weights(const float* __restrict__ Wih0, const float* __restrict__ Whh0,
                             const float* __restrict__ bih0, const float* __restrict__ bhh0,
                             const float* __restrict__ Wih1, const float* __restrict__ Whh1,
                             const float* __restrict__ bih1, const float* __restrict__ bhh1,
                             unsigned short* __restrict__ W0p, unsigned short* __restrict__ W1p,
                             float* __restrict__ b0, float* __restrict__ b1) {
  int e = blockIdx.x * 256 + threadIdx.x;
  const int N0 = 1024 * 416;
  const int N1 = 1024 * 512;
  if (e < N0) {
    int kk = e & 7, t1 = e >> 3;
    int n = t1 & 15, t2 = t1 >> 4;
    int kb = t2 % 52, nb = t2 / 52;
    int gn = nb * 16 + n, k = kb * 8 + kk;
    float v = (k < 160) ? Wih0[gn * 160 + k] : Whh0[gn * 256 + (k - 160)];
    W0p[e] = f2bf(v);
  } else if (e < N0 + N1) {
    int e2 = e - N0;
    int kk = e2 & 7, t1 = e2 >> 3;
    int n = t1 & 15, t2 = t1 >> 4;
    int kb = t2 & 63, nb = t2 >> 6;
    int gn = nb * 16 + n, k = kb * 8 + kk;
    float v = (k < 256) ? Wih1[gn * 256 + k] : Whh1[gn * 256 + (k - 256)];
    W1p[e2] = f2bf(v);
  } else if (e < N0 + N1 + 1024) {
    int n = e - (N0 + N1);
    b0[n] = bih0[n] + bhh0[n];
  } else if (e < N0 + N1 + 2048) {
    int n = e - (N0 + N1 + 1024);
    b1[n] = bih1[n] + bhh1[n];
  }
}

// ---------------- fused 2-layer LSTM + FC ----------------
// 256 blocks x 512 threads (8 waves). Block owns 64 batch rows for all 10 steps.
// LDS (88 KB -> 1 block/CU, 2 waves/SIMD):
//   lds_x: x_t tile, bf16 A-layout [kblk(20)][row(64)][8]   (k = 0..159 of layer0)
//   lds_h: kblk 0..31 = layer0 hidden h (== layer1 input h1), kblk 32..63 = layer1 hidden h2
//   c-state lives in registers in MFMA C/D layout (lane mapping fixed across steps).
// Wave w owns h-columns [w*32, w*32+32) (2 j-tiles of 16), all 64 rows (4 row-tiles),
// all 4 gates; per k-step: 4 A frags + 4 B frags -> 16 MFMAs.
__global__ __launch_bounds__(NTHREADS, 1)
void lstm_fused(const float* __restrict__ x,
                const unsigned short* __restrict__ W0p,
                const unsigned short* __restrict__ W1p,
                const float* __restrict__ b0,
                const float* __restrict__ b1,
                const float* __restrict__ Wfc,
                const float* __restrict__ bfc,
                float* __restrict__ out) {
  __shared__ unsigned int lds_x[20 * 64 * 4];   // 20480 B
  __shared__ unsigned int lds_h[64 * 64 * 4];   // 65536 B
  __shared__ float lds_red[64 * 8];             // 2048 B

  const int tid = threadIdx.x;
  const int wave = tid >> 6;
  const int lane = tid & 63;
  const int l15 = lane & 15;
  const int quad = lane >> 4;
  const long rowg0 = (long)blockIdx.x * 64;

  // zero h/c state (h1=h2=0 at t=0)
  for (int i = tid; i < 64 * 64 * 4; i += NTHREADS) lds_h[i] = 0u;

  f32x4 c0[2][4], c2[2][4];
#pragma unroll
  for (int jt = 0; jt < 2; jt++)
#pragma unroll
    for (int rt = 0; rt < 4; rt++) {
      c0[jt][rt] = (f32x4){0.f, 0.f, 0.f, 0.f};
      c2[jt][rt] = (f32x4){0.f, 0.f, 0.f, 0.f};
    }
  float fc_acc = 0.0f;

  const u32x4* lxs = (const u32x4*)lds_x;
  const u32x4* lhs = (const u32x4*)lds_h;
  unsigned short* lh16 = (unsigned short*)lds_h;
  const u32x4* w0q = (const u32x4*)W0p;
  const u32x4* w1q = (const u32x4*)W1p;

  for (int t = 0; t < 10; t++) {
    // ---- stage x_t -> lds_x (bf16, A-layout) ----
#pragma unroll
    for (int s = 0; s < 10; s++) {
      int p = tid + s * NTHREADS;          // 5120 bf16-pairs = 64 rows x 80 pairs
      int row = p / 80;
      int kp = p - row * 80;
      const float2 v = *(const float2*)(x + (rowg0 + row) * 1600 + t * 160 + kp * 2);
      lds_x[(kp >> 2) * 256 + row * 4 + (kp & 3)] =
          (unsigned)f2bf(v.x) | ((unsigned)f2bf(v.y) << 16);
    }
    __syncthreads();

    // ======== layer 0: K=416 ([x_t | h1_prev]) ========
    unsigned int hpk[2][4][2];
#pragma unroll
    for (int jt = 0; jt < 2; jt++) {
      f32x4 acc[4][4];
#pragma unroll
      for (int g = 0; g < 4; g++)
#pragma unroll
        for (int rt = 0; rt < 4; rt++) acc[g][rt] = (f32x4){0.f, 0.f, 0.f, 0.f};
      const int nbb = wave * 2 + jt;
#pragma unroll
      for (int ki = 0; ki < 13; ki++) {
        const int k0 = ki * 32;
        const u32x4* abase = (k0 < 160)
            ? (lxs + ((k0 >> 3) + quad) * 64)
            : (lhs + (((k0 - 160) >> 3) + quad) * 64);
        u32x4 av[4];
#pragma unroll
        for (int rt = 0; rt < 4; rt++) av[rt] = abase[rt * 16 + l15];
        u32x4 bv[4];
#pragma unroll
        for (int g = 0; g < 4; g++)
          bv[g] = w0q[((g * 16 + nbb) * 52 + (k0 >> 3) + quad) * 16 + l15];
#pragma unroll
        for (int g = 0; g < 4; g++)
#pragma unroll
          for (int rt = 0; rt < 4; rt++)
            acc[g][rt] = mfma_bf16(av[rt], bv[g], acc[g][rt]);
      }
      float bs[4];
#pragma unroll
      for (int g = 0; g < 4; g++) bs[g] = b0[g * 256 + wave * 32 + jt * 16 + l15];
#pragma unroll
      for (int rt = 0; rt < 4; rt++) {
        unsigned short hb[4];
#pragma unroll
        for (int r = 0; r < 4; r++) {
          float iv = sigm(acc[0][rt][r] + bs[0]);
          float fv = sigm(acc[1][rt][r] + bs[1]);
          float gv = tanh_fast(acc[2][rt][r] + bs[2]);
          float ov = sigm(acc[3][rt][r] + bs[3]);
          float cn = fv * c0[jt][rt][r] + iv * gv;
          c0[jt][rt][r] = cn;
          hb[r] = f2bf(ov * tanh_fast(cn));
        }
        hpk[jt][rt][0] = (unsigned)hb[0] | ((unsigned)hb[1] << 16);
        hpk[jt][rt][1] = (unsigned)hb[2] | ((unsigned)hb[3] << 16);
      }
    }
    __syncthreads();  // everyone done reading old h1
#pragma unroll
    for (int jt = 0; jt < 2; jt++)
#pragma unroll
      for (int rt = 0; rt < 4; rt++)
#pragma unroll
        for (int r = 0; r < 4; r++) {
          int row = rt * 16 + quad * 4 + r;
          int j = wave * 32 + jt * 16 + l15;
          unsigned v = hpk[jt][rt][r >> 1];
          lh16[((j >> 3) * 64 + row) * 8 + (j & 7)] =
              (unsigned short)((r & 1) ? (v >> 16) : (v & 0xffffu));
        }
    __syncthreads();

    // ======== layer 1: K=512 ([h1_t | h2_prev]) ========
#pragma unroll
    for (int jt = 0; jt < 2; jt++) {
      f32x4 acc[4][4];
#pragma unroll
      for (int g = 0; g < 4; g++)
#pragma unroll
        for (int rt = 0; rt < 4; rt++) acc[g][rt] = (f32x4){0.f, 0.f, 0.f, 0.f};
      const int nbb = wave * 2 + jt;
#pragma unroll
      for (int ki = 0; ki < 16; ki++) {
        const int k0 = ki * 32;
        const u32x4* abase = lhs + ((k0 >> 3) + quad) * 64;
        u32x4 av[4];
#pragma unroll
        for (int rt = 0; rt < 4; rt++) av[rt] = abase[rt * 16 + l15];
        u32x4 bv[4];
#pragma unroll
        for (int g = 0; g < 4; g++)
          bv[g] = w1q[((g * 16 + nbb) * 64 + (k0 >> 3) + quad) * 16 + l15];
#pragma unroll
        for (int g = 0; g < 4; g++)
#pragma unroll
          for (int rt = 0; rt < 4; rt++)
            acc[g][rt] = mfma_bf16(av[rt], bv[g], acc[g][rt]);
      }
      float bs[4];
#pragma unroll
      for (int g = 0; g < 4; g++) bs[g] = b1[g * 256 + wave * 32 + jt * 16 + l15];
#pragma unroll
      for (int rt = 0; rt < 4; rt++) {
        unsigned short hb[4];
#pragma unroll
        for (int r = 0; r < 4; r++) {
          float iv = sigm(acc[0][rt][r] + bs[0]);
          float fv = sigm(acc[1][rt][r] + bs[1]);
          float gv = tanh_fast(acc[2][rt][r] + bs[2]);
          float ov = sigm(acc[3][rt][r] + bs[3]);
          float cn = fv * c2[jt][rt][r] + iv * gv;
          c2[jt][rt][r] = cn;
          hb[r] = f2bf(ov * tanh_fast(cn));
        }
        hpk[jt][rt][0] = (unsigned)hb[0] | ((unsigned)hb[1] << 16);
        hpk[jt][rt][1] = (unsigned)hb[2] | ((unsigned)hb[3] << 16);
      }
    }
    __syncthreads();  // everyone done reading old h2
#pragma unroll
    for (int jt = 0; jt < 2; jt++)
#pragma unroll
      for (int rt = 0; rt < 4; rt++)
#pragma unroll
        for (int r = 0; r < 4; r++) {
          int row = rt * 16 + quad * 4 + r;
          int j = wave * 32 + jt * 16 + l15;
          unsigned v = hpk[jt][rt][r >> 1];
          lh16[((32 + (j >> 3)) * 64 + row) * 8 + (j & 7)] =
              (unsigned short)((r & 1) ? (v >> 16) : (v & 0xffffu));
        }
    __syncthreads();

    // ---- FC partial: logit += W_fc[t*256 + j] * h2[row][j] ----
    {
      int row = tid >> 3;
      int jq = (tid & 7) * 32;
      float s = 0.f;
#pragma unroll
      for (int kb = 0; kb < 4; kb++) {
        u32x4 hv = lhs[(32 + (jq >> 3) + kb) * 64 + row];
        const float* wf = Wfc + t * 256 + jq + kb * 8;
#pragma unroll
        for (int e = 0; e < 4; e++) {
          unsigned u = hv[e];
          s += bf2f((unsigned short)(u & 0xffffu)) * wf[2 * e];
          s += bf2f((unsigned short)(u >> 16)) * wf[2 * e + 1];
        }
      }
      fc_acc += s;
    }
    // no barrier needed: next-step staging touches lds_x only; h regions are
    // rewritten only after the next barrier pair.
  }

  lds_red[tid] = fc_acc;  // [row(64)][slot(8)], tid == row*8+slot
  __syncthreads();
  if (tid < 64) {
    float s = 0.f;
#pragma unroll
    for (int e = 0; e < 8; e++) s += lds_red[tid * 8 + e];
    out[rowg0 + tid] = sigm(s + bfc[0]);
  }
}

extern "C" void kernel_launch(void* const* d_in, const int* in_sizes, int n_in,
                              void* d_out, int out_size, void* d_ws, size_t ws_size,
                              hipStream_t stream) {
  const float* x    = (const float*)d_in[0];
  const float* Wih0 = (const float*)d_in[1];
  const float* Whh0 = (const float*)d_in[2];
  const float* bih0 = (const float*)d_in[3];
  const float* bhh0 = (const float*)d_in[4];
  const float* Wih1 = (const float*)d_in[5];
  const float* Whh1 = (const float*)d_in[6];
  const float* bih1 = (const float*)d_in[7];
  const float* bhh1 = (const float*)d_in[8];
  const float* Wfc  = (const float*)d_in[9];
  const float* bfc  = (const float*)d_in[10];
  float* out = (float*)d_out;

  unsigned short* W0p = (unsigned short*)d_ws;         // 1024*416 bf16
  unsigned short* W1p = W0p + 1024 * 416;              // 1024*512 bf16
  float* b0 = (float*)(W1p + 1024 * 512);              // 1024 f32 (16B aligned)
  float* b1 = b0 + 1024;                               // 1024 f32
  // total ws use: 1,908,736 bytes

  const int total = 1024 * 416 + 1024 * 512 + 2048;
  pack_weights<<<(total + 255) / 256, 256, 0, stream>>>(
      Wih0, Whh0, bih0, bhh0, Wih1, Whh1, bih1, bhh1, W0p, W1p, b0, b1);
  lstm_fused<<<256, NTHREADS, 0, stream>>>(x, W0p, W1p, b0, b1, Wfc, bfc, out);
}

// Round 2
// 1748.404 us; speedup vs baseline: 1.0463x; 1.0463x over previous
//
#include <hip/hip_runtime.h>

#define NTHREADS 512

typedef __attribute__((ext_vector_type(8))) short s16x8;
typedef __attribute__((ext_vector_type(4))) float f32x4;
typedef __attribute__((ext_vector_type(4))) unsigned int u32x4;

__device__ __forceinline__ unsigned short f2bf(float f) {
  unsigned u = __float_as_uint(f);
  u += 0x7fffu + ((u >> 16) & 1u);
  return (unsigned short)(u >> 16);
}
__device__ __forceinline__ float bf2f(unsigned short s) {
  return __uint_as_float(((unsigned)s) << 16);
}
__device__ __forceinline__ float sigm(float x) {
  return __builtin_amdgcn_rcpf(1.0f + __expf(-x));
}
__device__ __forceinline__ float tanh_fast(float x) {
  return 1.0f - 2.0f * __builtin_amdgcn_rcpf(1.0f + __expf(2.0f * x));
}
__device__ __forceinline__ f32x4 mfma_bf16(u32x4 a, u32x4 b, f32x4 c) {
  union { u32x4 u; s16x8 s; } ua, ub;
  ua.u = a; ub.u = b;
  return __builtin_amdgcn_mfma_f32_16x16x32_bf16(ua.s, ub.s, c, 0, 0, 0);
}

// ---------------- weight pre-pack ----------------
// W0p: layer0 combined [n=4H][K=416] (k<160: W_ih0, else W_hh0), bf16,
//      layout [nblk][kblk][16 n][8 k]  (B-fragment: wave reads 1KB contiguous)
// W1p: layer1 combined K=512 (k<256: W_ih1, else W_hh1), KB=64
// b0/b1: b_ih + b_hh pre-summed, f32
__global__ void pack_weights(const float* __restrict__ Wih0, const float* __restrict__ Whh0,
                             const float* __restrict__ bih0, const float* __restrict__ bhh0,
                             const float* __restrict__ Wih1, const float* __restrict__ Whh1,
                             const float* __restrict__ bih1, const float* __restrict__ bhh1,
                             unsigned short* __restrict__ W0p, unsigned short* __restrict__ W1p,
                             float* __restrict__ b0, float* __restrict__ b1) {
  int e = blockIdx.x * 256 + threadIdx.x;
  const int N0 = 1024 * 416;
  const int N1 = 1024 * 512;
  if (e < N0) {
    int kk = e & 7, t1 = e >> 3;
    int n = t1 & 15, t2 = t1 >> 4;
    int kb = t2 % 52, nb = t2 / 52;
    int gn = nb * 16 + n, k = kb * 8 + kk;
    float v = (k < 160) ? Wih0[gn * 160 + k] : Whh0[gn * 256 + (k - 160)];
    W0p[e] = f2bf(v);
  } else if (e < N0 + N1) {
    int e2 = e - N0;
    int kk = e2 & 7, t1 = e2 >> 3;
    int n = t1 & 15, t2 = t1 >> 4;
    int kb = t2 & 63, nb = t2 >> 6;
    int gn = nb * 16 + n, k = kb * 8 + kk;
    float v = (k < 256) ? Wih1[gn * 256 + k] : Whh1[gn * 256 + (k - 256)];
    W1p[e2] = f2bf(v);
  } else if (e < N0 + N1 + 1024) {
    int n = e - (N0 + N1);
    b0[n] = bih0[n] + bhh0[n];
  } else if (e < N0 + N1 + 2048) {
    int n = e - (N0 + N1 + 1024);
    b1[n] = bih1[n] + bhh1[n];
  }
}

// ---------------- fused 2-layer LSTM + FC ----------------
// 256 blocks x 512 threads (8 waves), block owns 64 batch rows for all 10 steps.
// LDS ~104 KB -> 1 block/CU (2 waves/SIMD); __launch_bounds__(512,2) -> VGPR
// cap 256 so the ~233-reg live set (acc 64 + bv 64 + av 16 + c-state 64 + addr)
// does NOT spill (round-1: 925 MB of scratch writes at VGPR=128).
// Depth-3 rolling prefetch of B fragments: loads for ki+3 issue before ki's
// MFMAs -> ~460 cyc latency cover per wave-pair.
__global__ __launch_bounds__(NTHREADS, 2)
void lstm_fused(const float* __restrict__ x,
                const unsigned short* __restrict__ W0p,
                const unsigned short* __restrict__ W1p,
                const float* __restrict__ b0,
                const float* __restrict__ b1,
                const float* __restrict__ Wfc,
                const float* __restrict__ bfc,
                float* __restrict__ out) {
  __shared__ unsigned int lds_x[20 * 64 * 4];   // 20480 B  x_t tile, bf16 A-layout
  __shared__ unsigned int lds_h[64 * 64 * 4];   // 65536 B  kblk 0..31: h1, 32..63: h2
  __shared__ float lds_red[64 * 8];             // 2048 B
  __shared__ float lds_b0[1024];                // 4096 B  (biases in LDS: keeps regs free)
  __shared__ float lds_b1[1024];                // 4096 B
  __shared__ float lds_wfc[2560];               // 10240 B

  const int tid = threadIdx.x;
  const int wave = tid >> 6;
  const int lane = tid & 63;
  const int l15 = lane & 15;
  const int quad = lane >> 4;
  const long rowg0 = (long)blockIdx.x * 64;

  // zero h state (h1=h2=0 at t=0) + stage biases/W_fc into LDS
  for (int i = tid; i < 64 * 64 * 4; i += NTHREADS) lds_h[i] = 0u;
  for (int i = tid; i < 1024; i += NTHREADS) { lds_b0[i] = b0[i]; lds_b1[i] = b1[i]; }
  for (int i = tid; i < 2560; i += NTHREADS) lds_wfc[i] = Wfc[i];

  f32x4 c0[2][4], c2[2][4];
#pragma unroll
  for (int jt = 0; jt < 2; jt++)
#pragma unroll
    for (int rt = 0; rt < 4; rt++) {
      c0[jt][rt] = (f32x4){0.f, 0.f, 0.f, 0.f};
      c2[jt][rt] = (f32x4){0.f, 0.f, 0.f, 0.f};
    }
  float fc_acc = 0.0f;

  const u32x4* lxs = (const u32x4*)lds_x;
  const u32x4* lhs = (const u32x4*)lds_h;
  unsigned short* lh16 = (unsigned short*)lds_h;
  const u32x4* w0q = (const u32x4*)W0p;
  const u32x4* w1q = (const u32x4*)W1p;

  for (int t = 0; t < 10; t++) {
    // ---- stage x_t -> lds_x (bf16 A-layout), nontemporal f32x4 loads ----
#pragma unroll
    for (int s = 0; s < 5; s++) {
      int p = tid + s * NTHREADS;          // 2560 f32x4 = 64 rows x 40 quads
      int row = p / 40;
      int kq = p - row * 40;
      const f32x4 v = __builtin_nontemporal_load(
          (const f32x4*)(x + (rowg0 + row) * 1600 + t * 160 + kq * 4));
      unsigned lo = (unsigned)f2bf(v[0]) | ((unsigned)f2bf(v[1]) << 16);
      unsigned hi = (unsigned)f2bf(v[2]) | ((unsigned)f2bf(v[3]) << 16);
      int base = (kq >> 1) * 256 + row * 4 + (kq & 1) * 2;
      lds_x[base] = lo;
      lds_x[base + 1] = hi;
    }
    __syncthreads();

    // ======== layer 0: K=416 ([x_t | h1_prev]) ========
    unsigned int hpk[2][4][2];
#pragma unroll
    for (int jt = 0; jt < 2; jt++) {
      f32x4 acc[4][4];
#pragma unroll
      for (int g = 0; g < 4; g++)
#pragma unroll
        for (int rt = 0; rt < 4; rt++) acc[g][rt] = (f32x4){0.f, 0.f, 0.f, 0.f};
      const int nbb = wave * 2 + jt;

      u32x4 bv[4][4];  // rolling slots: depth-3 prefetch
#pragma unroll
      for (int s = 0; s < 3; s++)
#pragma unroll
        for (int g = 0; g < 4; g++)
          bv[s][g] = w0q[((g * 16 + nbb) * 52 + s * 4 + quad) * 16 + l15];

#pragma unroll
      for (int ki = 0; ki < 13; ki++) {
        const int k0 = ki * 32;
        // prefetch B frags for ki+3 (slot consumed at ki-1)
        if (ki + 3 < 13) {
#pragma unroll
          for (int g = 0; g < 4; g++)
            bv[(ki + 3) & 3][g] =
                w0q[((g * 16 + nbb) * 52 + (ki + 3) * 4 + quad) * 16 + l15];
        }
        const u32x4* abase = (k0 < 160)
            ? (lxs + ((k0 >> 3) + quad) * 64)
            : (lhs + (((k0 - 160) >> 3) + quad) * 64);
        u32x4 av[4];
#pragma unroll
        for (int rt = 0; rt < 4; rt++) av[rt] = abase[rt * 16 + l15];
#pragma unroll
        for (int g = 0; g < 4; g++)
#pragma unroll
          for (int rt = 0; rt < 4; rt++)
            acc[g][rt] = mfma_bf16(av[rt], bv[ki & 3][g], acc[g][rt]);
      }
      float bs[4];
#pragma unroll
      for (int g = 0; g < 4; g++) bs[g] = lds_b0[g * 256 + wave * 32 + jt * 16 + l15];
#pragma unroll
      for (int rt = 0; rt < 4; rt++) {
        unsigned short hb[4];
#pragma unroll
        for (int r = 0; r < 4; r++) {
          float iv = sigm(acc[0][rt][r] + bs[0]);
          float fv = sigm(acc[1][rt][r] + bs[1]);
          float gv = tanh_fast(acc[2][rt][r] + bs[2]);
          float ov = sigm(acc[3][rt][r] + bs[3]);
          float cn = fv * c0[jt][rt][r] + iv * gv;
          c0[jt][rt][r] = cn;
          hb[r] = f2bf(ov * tanh_fast(cn));
        }
        hpk[jt][rt][0] = (unsigned)hb[0] | ((unsigned)hb[1] << 16);
        hpk[jt][rt][1] = (unsigned)hb[2] | ((unsigned)hb[3] << 16);
      }
    }
    __syncthreads();  // everyone done reading old h1
#pragma unroll
    for (int jt = 0; jt < 2; jt++)
#pragma unroll
      for (int rt = 0; rt < 4; rt++)
#pragma unroll
        for (int r = 0; r < 4; r++) {
          int row = rt * 16 + quad * 4 + r;
          int j = wave * 32 + jt * 16 + l15;
          unsigned v = hpk[jt][rt][r >> 1];
          lh16[((j >> 3) * 64 + row) * 8 + (j & 7)] =
              (unsigned short)((r & 1) ? (v >> 16) : (v & 0xffffu));
        }
    __syncthreads();

    // ======== layer 1: K=512 ([h1_t | h2_prev]) ========
#pragma unroll
    for (int jt = 0; jt < 2; jt++) {
      f32x4 acc[4][4];
#pragma unroll
      for (int g = 0; g < 4; g++)
#pragma unroll
        for (int rt = 0; rt < 4; rt++) acc[g][rt] = (f32x4){0.f, 0.f, 0.f, 0.f};
      const int nbb = wave * 2 + jt;

      u32x4 bv[4][4];
#pragma unroll
      for (int s = 0; s < 3; s++)
#pragma unroll
        for (int g = 0; g < 4; g++)
          bv[s][g] = w1q[((g * 16 + nbb) * 64 + s * 4 + quad) * 16 + l15];

#pragma unroll
      for (int ki = 0; ki < 16; ki++) {
        const int k0 = ki * 32;
        if (ki + 3 < 16) {
#pragma unroll
          for (int g = 0; g < 4; g++)
            bv[(ki + 3) & 3][g] =
                w1q[((g * 16 + nbb) * 64 + (ki + 3) * 4 + quad) * 16 + l15];
        }
        const u32x4* abase = lhs + ((k0 >> 3) + quad) * 64;
        u32x4 av[4];
#pragma unroll
        for (int rt = 0; rt < 4; rt++) av[rt] = abase[rt * 16 + l15];
#pragma unroll
        for (int g = 0; g < 4; g++)
#pragma unroll
          for (int rt = 0; rt < 4; rt++)
            acc[g][rt] = mfma_bf16(av[rt], bv[ki & 3][g], acc[g][rt]);
      }
      float bs[4];
#pragma unroll
      for (int g = 0; g < 4; g++) bs[g] = lds_b1[g * 256 + wave * 32 + jt * 16 + l15];
#pragma unroll
      for (int rt = 0; rt < 4; rt++) {
        unsigned short hb[4];
#pragma unroll
        for (int r = 0; r < 4; r++) {
          float iv = sigm(acc[0][rt][r] + bs[0]);
          float fv = sigm(acc[1][rt][r] + bs[1]);
          float gv = tanh_fast(acc[2][rt][r] + bs[2]);
          float ov = sigm(acc[3][rt][r] + bs[3]);
          float cn = fv * c2[jt][rt][r] + iv * gv;
          c2[jt][rt][r] = cn;
          hb[r] = f2bf(ov * tanh_fast(cn));
        }
        hpk[jt][rt][0] = (unsigned)hb[0] | ((unsigned)hb[1] << 16);
        hpk[jt][rt][1] = (unsigned)hb[2] | ((unsigned)hb[3] << 16);
      }
    }
    __syncthreads();  // everyone done reading old h2
#pragma unroll
    for (int jt = 0; jt < 2; jt++)
#pragma unroll
      for (int rt = 0; rt < 4; rt++)
#pragma unroll
        for (int r = 0; r < 4; r++) {
          int row = rt * 16 + quad * 4 + r;
          int j = wave * 32 + jt * 16 + l15;
          unsigned v = hpk[jt][rt][r >> 1];
          lh16[((32 + (j >> 3)) * 64 + row) * 8 + (j & 7)] =
              (unsigned short)((r & 1) ? (v >> 16) : (v & 0xffffu));
        }
    __syncthreads();

    // ---- FC partial: logit += W_fc[t*256 + j] * h2[row][j] ----
    {
      int row = tid >> 3;
      int jq = (tid & 7) * 32;
      float s = 0.f;
#pragma unroll
      for (int kb = 0; kb < 4; kb++) {
        u32x4 hv = lhs[(32 + (jq >> 3) + kb) * 64 + row];
        const float* wf = lds_wfc + t * 256 + jq + kb * 8;
#pragma unroll
        for (int e = 0; e < 4; e++) {
          unsigned u = hv[e];
          s += bf2f((unsigned short)(u & 0xffffu)) * wf[2 * e];
          s += bf2f((unsigned short)(u >> 16)) * wf[2 * e + 1];
        }
      }
      fc_acc += s;
    }
    // no barrier needed: next-step staging touches lds_x only; h regions are
    // rewritten only after the next barrier pair.
  }

  lds_red[tid] = fc_acc;  // [row(64)][slot(8)]
  __syncthreads();
  if (tid < 64) {
    float s = 0.f;
#pragma unroll
    for (int e = 0; e < 8; e++) s += lds_red[tid * 8 + e];
    out[rowg0 + tid] = sigm(s + bfc[0]);
  }
}

extern "C" void kernel_launch(void* const* d_in, const int* in_sizes, int n_in,
                              void* d_out, int out_size, void* d_ws, size_t ws_size,
                              hipStream_t stream) {
  const float* x    = (const float*)d_in[0];
  const float* Wih0 = (const float*)d_in[1];
  const float* Whh0 = (const float*)d_in[2];
  const float* bih0 = (const float*)d_in[3];
  const float* bhh0 = (const float*)d_in[4];
  const float* Wih1 = (const float*)d_in[5];
  const float* Whh1 = (const float*)d_in[6];
  const float* bih1 = (const float*)d_in[7];
  const float* bhh1 = (const float*)d_in[8];
  const float* Wfc  = (const float*)d_in[9];
  const float* bfc  = (const float*)d_in[10];
  float* out = (float*)d_out;

  unsigned short* W0p = (unsigned short*)d_ws;         // 1024*416 bf16
  unsigned short* W1p = W0p + 1024 * 416;              // 1024*512 bf16
  float* b0 = (float*)(W1p + 1024 * 512);              // 1024 f32
  float* b1 = b0 + 1024;                               // 1024 f32

  const int total = 1024 * 416 + 1024 * 512 + 2048;
  pack_weights<<<(total + 255) / 256, 256, 0, stream>>>(
      Wih0, Whh0, bih0, bhh0, Wih1, Whh1, bih1, bhh1, W0p, W1p, b0, b1);
  lstm_fused<<<256, NTHREADS, 0, stream>>>(x, W0p, W1p, b0, b1, Wfc, bfc, out);
}